// Round 4
// baseline (794.688 us; speedup 1.0000x reference)
//
#include <hip/hip_runtime.h>
#include <math.h>

// ---- constants -------------------------------------------------------------
#define BATCH   32
#define LSEQ    1000
#define NHEADS  8
#define CHUNK   64                               // keys per attn work item
#define NCHUNK  16                               // ceil(1000/64)
#define NBLK    512                              // 2 blocks/CU, capacity-guaranteed
#define PE_C    (-9.210340371976184f / 512.0f)   // -ln(10000)/512

// pe[j][e]: even e -> sin(j*10000^(-e/512)), odd e -> cos with freq of e-1
__device__ __forceinline__ float pe_val(int j, int e) {
  int ef = e & ~1;
  float dv  = __expf((float)ef * PE_C);
  float arg = (float)j * dv;
  return (e & 1) ? __cosf(arg) : __sinf(arg);
}

// ---- contention-free grid barrier ------------------------------------------
// Each block release-stores an epoch to ITS OWN flag (no RMW, no shared line).
// Waiters: lane t acquire-loads flags[t] (+flags[t+256]) -> coalesced reads
// spread over 16 cachelines; __syncthreads_and decides; s_sleep throttles
// the buffer_inv storm so co-resident working blocks keep their L1.
__device__ __forceinline__ void gbar_signal(unsigned* flags, unsigned phase) {
  __syncthreads();                               // all block work done
  if (threadIdx.x == 0)
    __hip_atomic_store(flags + blockIdx.x, phase, __ATOMIC_RELEASE,
                       __HIP_MEMORY_SCOPE_AGENT);
}
__device__ __forceinline__ void gbar_wait(unsigned* flags, unsigned phase,
                                          int nflags) {
  int t = threadIdx.x;
  for (;;) {
    unsigned a = __hip_atomic_load(flags + t, __ATOMIC_ACQUIRE,
                                   __HIP_MEMORY_SCOPE_AGENT);
    unsigned b = (nflags > 256)
                     ? __hip_atomic_load(flags + t + 256, __ATOMIC_ACQUIRE,
                                         __HIP_MEMORY_SCOPE_AGENT)
                     : phase;
    if (__syncthreads_and((int)(a >= phase && b >= phase))) break;
    __builtin_amdgcn_s_sleep(8);
  }
}

// One kernel, 5 phases separated by flag barriers:
//  A: blocks 0..255 -> qfold (b,h); blocks 256..511 -> pe_tab[1000][512]
//  B: MD[r][bh] = row_r · wf[bh], 628 items grid-strided
//  C: attn scores + chunk softmax + weighted emb/pe sum, 1 item/block
//  D1: blocks 0..255 -> per-(b,h) combine y + Wv matvec -> ctx
//  D2: blocks 0..31  -> MLP1 + MLP2 (others exit after signaling)
__global__ __launch_bounds__(256, 2) void fused_kernel(
    const int* __restrict__ data, const int* __restrict__ lengths,
    const float* __restrict__ emb,
    const float* __restrict__ Wq, const float* __restrict__ bq,
    const float* __restrict__ Wk, const float* __restrict__ bk,
    const float* __restrict__ Wv, const float* __restrict__ bv,
    const float* __restrict__ W1, const float* __restrict__ b1,
    const float* __restrict__ W2, const float* __restrict__ b2,
    float* __restrict__ wfT4, float* __restrict__ bias_dot,
    float* __restrict__ MD, float* __restrict__ pe_tab,
    float* __restrict__ mS, float* __restrict__ y_part,
    float* __restrict__ ctx_g, unsigned* __restrict__ flags,
    float* __restrict__ out) {
  __shared__ float smem[5400];                   // 21.6 KB union of all phases
  int bid = blockIdx.x;
  int t   = threadIdx.x;

  // ======================== Phase A ========================
  if (bid < 256) {
    float* xs  = smem;                           // 512
    float* red = smem + 512;                     // 256
    float* qs  = smem + 768;                     // 64
    int h = bid & 7, b = bid >> 3;
    int p = lengths[b] - 1;
    int tok = data[b * LSEQ + p];
    const float* er = emb + (size_t)tok * 512;
    xs[t]       = er[t]       + pe_val(p, t);
    xs[t + 256] = er[t + 256] + pe_val(p, t + 256);
    __syncthreads();
    // Wq matvec, 4-way K-split
    int col = h * 64 + (t & 63);
    int kp  = t >> 6;
    {
      const float* wr = Wq + (size_t)col * 512 + kp * 128;
      const float* xp = xs + kp * 128;
      float a = 0.0f;
      for (int e = 0; e < 128; e += 4) {
        float4 wv = *(const float4*)(wr + e);
        a += wv.x * xp[e] + wv.y * xp[e + 1] + wv.z * xp[e + 2] + wv.w * xp[e + 3];
      }
      red[t] = a;
    }
    __syncthreads();
    if (t < 64) {
      float qval = (red[t] + red[t + 64] + red[t + 128] + red[t + 192]
                    + bq[h * 64 + t]) * 0.125f;  // fold in 1/sqrt(64)
      qs[t] = qval;
      float bd = qval * bk[h * 64 + t];
      #pragma unroll
      for (int o = 32; o > 0; o >>= 1) bd += __shfl_xor(bd, o, 64);
      if (t == 0) bias_dot[b * NHEADS + h] = bd;
    }
    __syncthreads();
    // fold q̂ through Wk: wf[e] = sum_d qs[d] * Wk[(h*64+d)*512 + e]
    float a0 = 0.0f, a1 = 0.0f;
    const float* wkb = Wk + (size_t)(h * 64) * 512;
    for (int d = 0; d < 64; ++d) {
      float qd = qs[d];
      a0 += qd * wkb[d * 512 + t];
      a1 += qd * wkb[d * 512 + t + 256];
    }
    int bh = b * NHEADS + h;
    int e1 = t, e2 = t + 256;
    wfT4[(e1 >> 2) * 1024 + bh * 4 + (e1 & 3)] = a0;
    wfT4[(e2 >> 2) * 1024 + bh * 4 + (e2 & 3)] = a1;
  } else {
    // pe table rows j = bid-256, +256, ... (~4 rows per block)
    int e0 = t * 2;
    float dvp = __expf((float)e0 * PE_C);        // same expr as original trig
    for (int j = bid - 256; j < LSEQ; j += 256) {
      float arg = (float)j * dvp;
      float2 v;
      v.x = __sinf(arg);
      v.y = __cosf(arg);
      *(float2*)(pe_tab + (size_t)j * 512 + e0) = v;
    }
  }
  gbar_signal(flags, 1);
  gbar_wait(flags, 1, NBLK);

  // ======================== Phase B ========================
  {
    float* rows = smem;                          // 8 rows x 516 (pad 4)
    for (int wi = bid; wi < 628; wi += NBLK) {
      __syncthreads();                           // protect smem reuse
      int r0  = (wi % 157) * 8;
      int bh0 = (wi / 157) * 64;
      #pragma unroll
      for (int i = 0; i < 4; ++i) {
        int fi = t + i * 256;                    // float4 index 0..1023
        int rr = fi >> 7;                        // local row
        int e  = (fi & 127) * 4;
        int rg = r0 + rr;
        float4 v;
        if (rg < 256) v = *(const float4*)(emb + (size_t)rg * 512 + e);
        else          v = *(const float4*)(pe_tab + (size_t)(rg - 256) * 512 + e);
        *(float4*)(&rows[rr * 516 + e]) = v;
      }
      __syncthreads();
      int w    = t >> 6, lane = t & 63;
      int bh   = bh0 + w * 16 + (lane & 15);     // wave-distinct bh strip
      int rp   = lane >> 4;                      // row pair within strip
      const float* rw0 = rows + (2 * rp) * 516;
      const float* rw1 = rows + (2 * rp + 1) * 516;
      const float* wp  = wfT4 + (size_t)bh * 4;
      float a0 = 0.0f, a1 = 0.0f;
      #pragma unroll 8
      for (int g = 0; g < 128; ++g) {
        float4 w4 = *(const float4*)(wp + (size_t)g * 1024);
        float4 v0 = *(const float4*)(rw0 + 4 * g);
        float4 v1 = *(const float4*)(rw1 + 4 * g);
        a0 += v0.x * w4.x + v0.y * w4.y + v0.z * w4.z + v0.w * w4.w;
        a1 += v1.x * w4.x + v1.y * w4.y + v1.z * w4.z + v1.w * w4.w;
      }
      float bd = (r0 < 256) ? bias_dot[bh] : 0.0f;
      int r = r0 + 2 * rp;
      MD[(size_t)r * 256 + bh]       = a0 + bd;
      MD[(size_t)(r + 1) * 256 + bh] = a1 + bd;
    }
  }
  gbar_signal(flags, 2);
  gbar_wait(flags, 2, NBLK);

  // ======================== Phase C ========================
  {
    int jc = bid & 15, b = bid >> 4;             // exactly 1 item/block
    int n  = lengths[b];
    int j0 = jc * CHUNK;
    if (j0 < n) {                                // block-uniform guard
      int cnt = min(CHUNK, n - j0);
      float* sl   = smem;                        // [64][8] probs
      float* redw = smem + 512;                  // [4][8]
      float* m_sh = smem + 544;                  // [8]
      float* s_sh = smem + 552;                  // [8]
      int*   tk   = (int*)(smem + 560);          // [64]
      const float* Edot = MD;                    // [256 tok][256 bh] (+bias)
      const float* Pdot = MD + 256 * 256;        // [1000 pos][256 bh]

      if (t < CHUNK) tk[t] = data[b * LSEQ + j0 + ((t < cnt) ? t : 0)];
      __syncthreads();

      // scores: thread handles (jA,h) and (jB=jA+32,h)
      int h = t & 7, jA = t >> 3, jB = jA + 32;
      int bh8 = b * 8 + h;
      float sA = -INFINITY, sB = -INFINITY;
      if (jA < cnt)
        sA = Edot[(size_t)tk[jA] * 256 + bh8] + Pdot[(size_t)(j0 + jA) * 256 + bh8];
      if (jB < cnt)
        sB = Edot[(size_t)tk[jB] * 256 + bh8] + Pdot[(size_t)(j0 + jB) * 256 + bh8];

      int w = t >> 6;
      float mloc = fmaxf(sA, sB);
      #pragma unroll
      for (int o = 8; o < 64; o <<= 1) mloc = fmaxf(mloc, __shfl_xor(mloc, o, 64));
      if ((t & 63) < 8) redw[w * 8 + (t & 7)] = mloc;
      __syncthreads();
      if (t < 8)
        m_sh[t] = fmaxf(fmaxf(redw[t], redw[8 + t]),
                        fmaxf(redw[16 + t], redw[24 + t]));
      __syncthreads();
      float mh = m_sh[h];
      float pA = __expf(sA - mh);                // exp(-inf)=0 for invalid j
      float pB = __expf(sB - mh);
      sl[jA * 8 + h] = pA;
      sl[jB * 8 + h] = pB;
      float sloc = pA + pB;
      #pragma unroll
      for (int o = 8; o < 64; o <<= 1) sloc += __shfl_xor(sloc, o, 64);
      if ((t & 63) < 8) redw[w * 8 + (t & 7)] = sloc;
      __syncthreads();                           // also publishes sl[]
      if (t < 8) s_sh[t] = redw[t] + redw[8 + t] + redw[16 + t] + redw[24 + t];

      // y accumulation; wave owns e-slice, lane owns (sin,cos) pair
      int lane = t & 63;
      int e0i = w * 128 + lane * 2;
      float acc0[8] = {0, 0, 0, 0, 0, 0, 0, 0};
      float acc1[8] = {0, 0, 0, 0, 0, 0, 0, 0};
      const float* pe_row = pe_tab + (size_t)j0 * 512 + e0i;
      #pragma unroll 4
      for (int jj = 0; jj < cnt; ++jj) {
        int tok = tk[jj];
        float2 ev = *(const float2*)(emb + (size_t)tok * 512 + e0i);
        float2 pv = *(const float2*)(pe_row + (size_t)jj * 512);
        float x0 = ev.x + pv.x;
        float x1 = ev.y + pv.y;
        float4 pa = *(const float4*)(&sl[jj * 8]);
        float4 pb = *(const float4*)(&sl[jj * 8 + 4]);
        acc0[0] += pa.x * x0; acc1[0] += pa.x * x1;
        acc0[1] += pa.y * x0; acc1[1] += pa.y * x1;
        acc0[2] += pa.z * x0; acc1[2] += pa.z * x1;
        acc0[3] += pa.w * x0; acc1[3] += pa.w * x1;
        acc0[4] += pb.x * x0; acc1[4] += pb.x * x1;
        acc0[5] += pb.y * x0; acc1[5] += pb.y * x1;
        acc0[6] += pb.z * x0; acc1[6] += pb.z * x1;
        acc0[7] += pb.w * x0; acc1[7] += pb.w * x1;
      }
      size_t base = (size_t)(b * NCHUNK + jc) * 4096 + e0i;
      #pragma unroll
      for (int hh = 0; hh < 8; ++hh) {
        float2 o; o.x = acc0[hh]; o.y = acc1[hh];
        *(float2*)(y_part + base + hh * 512) = o;
      }
      if (t < 8) {
        float2 ms; ms.x = m_sh[t]; ms.y = s_sh[t];
        *(float2*)(mS + ((size_t)(b * NCHUNK + jc) * 8 + t) * 2) = ms;
      }
    }
  }
  gbar_signal(flags, 3);
  gbar_wait(flags, 3, NBLK);

  // ======================== Phase D1: per-(b,h) combine + Wv matvec ========
  if (bid < 256) {
    int h = bid & 7, b = bid >> 3;
    float* ys  = smem;                           // 512
    float* red = smem + 512;                     // 256
    int n  = lengths[b];
    int nc = (n + CHUNK - 1) / CHUNK;
    float M = -INFINITY;
    for (int jc = 0; jc < nc; ++jc)
      M = fmaxf(M, mS[((size_t)(b * NCHUNK + jc) * 8 + h) * 2]);
    float S = 0.0f, s0 = 0.0f, s1 = 0.0f;
    for (int jc = 0; jc < nc; ++jc) {
      float2 ms = *(const float2*)(mS + ((size_t)(b * NCHUNK + jc) * 8 + h) * 2);
      float wgt = __expf(ms.x - M);
      S += wgt * ms.y;
      size_t base = (size_t)(b * NCHUNK + jc) * 4096 + h * 512;
      s0 += wgt * y_part[base + t];
      s1 += wgt * y_part[base + t + 256];
    }
    float inv = 1.0f / S;
    ys[t]       = s0 * inv;
    ys[t + 256] = s1 * inv;
    __syncthreads();
    // ctx slice = Wv_h · y_h + bv (4-way K-split, same red tree as split K4)
    int col = h * 64 + (t & 63);
    int kp  = t >> 6;
    const float* wr = Wv + (size_t)col * 512 + kp * 128;
    const float* xp = ys + kp * 128;
    float a = 0.0f;
    for (int e = 0; e < 128; e += 4) {
      float4 wv4 = *(const float4*)(wr + e);
      a += wv4.x * xp[e] + wv4.y * xp[e + 1] + wv4.z * xp[e + 2] + wv4.w * xp[e + 3];
    }
    red[t] = a;
    __syncthreads();
    if (t < 64)
      ctx_g[b * 512 + h * 64 + t] =
          red[t] + red[t + 64] + red[t + 128] + red[t + 192] + bv[h * 64 + t];
  }
  gbar_signal(flags, 4);
  if (bid >= BATCH) return;                      // everyone else is done
  gbar_wait(flags, 4, 256);                      // ctx written by blocks 0..255

  // ======================== Phase D2: MLP (blocks 0..31) ===================
  {
    int b = bid;
    float* xs   = smem;                          // 512
    float* red  = smem + 512;                    // 256
    float* hs_s = smem + 768;                    // 512
    float* o8   = smem + 1280;                   // 8
    xs[t]       = ctx_g[b * 512 + t];
    xs[t + 256] = ctx_g[b * 512 + t + 256];
    __syncthreads();
    // mlp1 (replicates split K5)
    for (int ch = 0; ch < 8; ++ch) {
      int col = ch * 64 + (t & 63);
      int kp  = t >> 6;
      const float* wr = W1 + (size_t)col * 512 + kp * 128;
      const float* xp = xs + kp * 128;
      float a = 0.0f;
      for (int e = 0; e < 128; e += 4) {
        float4 wv = *(const float4*)(wr + e);
        a += wv.x * xp[e] + wv.y * xp[e + 1] + wv.z * xp[e + 2] + wv.w * xp[e + 3];
      }
      red[t] = a;
      __syncthreads();
      if (t < 64) {
        float v = red[t] + red[t + 64] + red[t + 128] + red[t + 192] + b1[ch * 64 + t];
        hs_s[ch * 64 + t] = (v > 0.0f) ? v : 0.01f * v;
      }
      __syncthreads();
    }
    // mlp2 + mean + leaky (replicates split K6)
    int j = t >> 5, sub = t & 31;
    const float* w2r = W2 + (size_t)j * 512;
    float part = 0.0f;
    for (int e = sub * 16; e < sub * 16 + 16; e += 4) {
      float4 wv = *(const float4*)(w2r + e);
      float4 hv = *(const float4*)(hs_s + e);
      part += wv.x * hv.x + wv.y * hv.y + wv.z * hv.z + wv.w * hv.w;
    }
    #pragma unroll
    for (int o = 16; o > 0; o >>= 1) part += __shfl_xor(part, o, 64);
    if (sub == 0) o8[j] = fmaxf(part + b2[j], 0.0f);   // relu
    __syncthreads();
    if (t == 0) {
      float m = 0.0f;
      #pragma unroll
      for (int i = 0; i < 8; ++i) m += o8[i];
      m *= 0.125f;
      out[b] = (m > 0.0f) ? m : 0.01f * m;
    }
  }
}

// ---- launcher --------------------------------------------------------------
extern "C" void kernel_launch(void* const* d_in, const int* in_sizes, int n_in,
                              void* d_out, int out_size, void* d_ws, size_t ws_size,
                              hipStream_t stream) {
  const int*   data    = (const int*)d_in[0];
  const int*   lengths = (const int*)d_in[1];
  const float* emb     = (const float*)d_in[2];
  const float* Wq      = (const float*)d_in[3];
  const float* bq      = (const float*)d_in[4];
  const float* Wk      = (const float*)d_in[5];
  const float* bk      = (const float*)d_in[6];
  const float* Wv      = (const float*)d_in[7];
  const float* bv      = (const float*)d_in[8];
  const float* W1      = (const float*)d_in[9];
  const float* b1      = (const float*)d_in[10];
  const float* W2      = (const float*)d_in[11];
  const float* b2      = (const float*)d_in[12];
  float* out = (float*)d_out;

  char* ws = (char*)d_ws;
  float*    wfT4     = (float*)(ws);              //   524,288 B [e/4][256bh][4]
  float*    MD       = (float*)(ws + 524288);     // 1,286,144 B [1256][256bh]
  float*    bias_dot = (float*)(ws + 1810432);    //     1,024 B
  float*    mS       = (float*)(ws + 1811456);    //    32,768 B [b][16jc][h](m,S)
  float*    y_part   = (float*)(ws + 1844224);    // 8,388,608 B [b][16jc][8h][512]
  float*    pe_tab   = (float*)(ws + 10363904);   // 2,048,000 B [1000][512]
  float*    ctx_g    = (float*)(ws + 12411904);   //    65,536 B [32][512]
  unsigned* flags    = (unsigned*)(ws + 12477440); //    2,048 B barrier flags

  // zero barrier flags (workspace poisoned each iteration); graph-capture-safe
  hipMemsetAsync(flags, 0, NBLK * sizeof(unsigned), stream);

  fused_kernel<<<dim3(NBLK), dim3(256), 0, stream>>>(
      data, lengths, emb, Wq, bq, Wk, bk, Wv, bv, W1, b1, W2, b2,
      wfT4, bias_dot, MD, pe_tab, mS, y_part, ctx_g, flags, out);
}

// Round 5
// 224.645 us; speedup vs baseline: 3.5375x; 3.5375x over previous
//
#include <hip/hip_runtime.h>
#include <math.h>

// ---- constants -------------------------------------------------------------
#define BATCH   32
#define LSEQ    1000
#define NHEADS  8
#define CHUNK   64                               // keys per attn work item
#define NCHUNK  16                               // ceil(1000/64)
#define NBLK    512                              // 2 blocks/CU, capacity-guaranteed
#define PE_C    (-9.210340371976184f / 512.0f)   // -ln(10000)/512

// pe[j][e]: even e -> sin(j*10000^(-e/512)), odd e -> cos with freq of e-1
__device__ __forceinline__ float pe_val(int j, int e) {
  int ef = e & ~1;
  float dv  = __expf((float)ef * PE_C);
  float arg = (float)j * dv;
  return (e & 1) ? __cosf(arg) : __sinf(arg);
}

// ---- hierarchical grid barrier ---------------------------------------------
// r3 (contended RMW counter): ~83us/barrier. r4 (256 threads/block ACQUIRE-
// polling 32 lines): ~150us/barrier -- every acquire poll invalidates L1/L2
// and refetches the whole flag array from LLC. r5: arrival = one release-store
// per block to its own flag; ONLY block 0 polls the array with RELAXED agent
// loads (LLC read, no invalidation); broadcast = one go-word; ONLY thread 0
// of each waiter polls it relaxed + one final ACQUIRE for cumulativity.
__device__ __forceinline__ void bar_signal(unsigned* flags, unsigned phase) {
  __syncthreads();                               // block work done
  if (threadIdx.x == 0)
    __hip_atomic_store(flags + blockIdx.x, phase, __ATOMIC_RELEASE,
                       __HIP_MEMORY_SCOPE_AGENT);
}

__device__ __forceinline__ void bar_finish(unsigned* flags, unsigned* go,
                                           unsigned phase, int nsig) {
  int t = threadIdx.x;
  if (blockIdx.x == 0) {
    // aggregator: relaxed polls (no cache invalidation), and-reduce per round
    for (;;) {
      unsigned a = __hip_atomic_load(flags + t, __ATOMIC_RELAXED,
                                     __HIP_MEMORY_SCOPE_AGENT);
      unsigned b = (nsig > 256)
                       ? __hip_atomic_load(flags + t + 256, __ATOMIC_RELAXED,
                                           __HIP_MEMORY_SCOPE_AGENT)
                       : phase;
      if (__syncthreads_and((int)(a >= phase && b >= phase))) break;
      __builtin_amdgcn_s_sleep(1);
    }
    // cumulativity: acquire-load each flag once (sync-with every releaser)
    (void)__hip_atomic_load(flags + t, __ATOMIC_ACQUIRE,
                            __HIP_MEMORY_SCOPE_AGENT);
    if (nsig > 256)
      (void)__hip_atomic_load(flags + t + 256, __ATOMIC_ACQUIRE,
                              __HIP_MEMORY_SCOPE_AGENT);
    __syncthreads();
    if (t == 0)
      __hip_atomic_store(go, phase, __ATOMIC_RELEASE,
                         __HIP_MEMORY_SCOPE_AGENT);
    // block 0 proceeds: it has acquired all writers directly
  } else {
    if (t == 0) {
      unsigned g;
      do {
        g = __hip_atomic_load(go, __ATOMIC_RELAXED, __HIP_MEMORY_SCOPE_AGENT);
        if (g < phase) __builtin_amdgcn_s_sleep(8);
      } while (g < phase);
      (void)__hip_atomic_load(go, __ATOMIC_ACQUIRE,
                              __HIP_MEMORY_SCOPE_AGENT);  // sync-with agg
    }
    __syncthreads();
  }
}

// One kernel, 5 phases separated by hierarchical barriers:
//  A: blocks 0..255 -> qfold (b,h); blocks 256..511 -> pe_tab[1000][512]
//  B: MD[r][bh] = row_r · wf[bh], 628 items grid-strided
//  C: attn scores + chunk softmax + weighted emb/pe sum, 1 item/block
//  D1: blocks 0..255 -> per-(b,h) combine y + Wv matvec -> ctx
//  D2: blocks 0..31  -> MLP1 + MLP2
__global__ __launch_bounds__(256, 2) void fused_kernel(
    const int* __restrict__ data, const int* __restrict__ lengths,
    const float* __restrict__ emb,
    const float* __restrict__ Wq, const float* __restrict__ bq,
    const float* __restrict__ Wk, const float* __restrict__ bk,
    const float* __restrict__ Wv, const float* __restrict__ bv,
    const float* __restrict__ W1, const float* __restrict__ b1,
    const float* __restrict__ W2, const float* __restrict__ b2,
    float* __restrict__ wfT4, float* __restrict__ bias_dot,
    float* __restrict__ MD, float* __restrict__ pe_tab,
    float* __restrict__ mS, float* __restrict__ y_part,
    float* __restrict__ ctx_g, unsigned* __restrict__ flags,
    unsigned* __restrict__ go, float* __restrict__ out) {
  __shared__ float smem[5400];                   // 21.6 KB union of all phases
  int bid = blockIdx.x;
  int t   = threadIdx.x;

  // ======================== Phase A ========================
  if (bid < 256) {
    float* xs  = smem;                           // 512
    float* red = smem + 512;                     // 256
    float* qs  = smem + 768;                     // 64
    int h = bid & 7, b = bid >> 3;
    int p = lengths[b] - 1;
    int tok = data[b * LSEQ + p];
    const float* er = emb + (size_t)tok * 512;
    xs[t]       = er[t]       + pe_val(p, t);
    xs[t + 256] = er[t + 256] + pe_val(p, t + 256);
    __syncthreads();
    // Wq matvec, 4-way K-split
    int col = h * 64 + (t & 63);
    int kp  = t >> 6;
    {
      const float* wr = Wq + (size_t)col * 512 + kp * 128;
      const float* xp = xs + kp * 128;
      float a = 0.0f;
      for (int e = 0; e < 128; e += 4) {
        float4 wv = *(const float4*)(wr + e);
        a += wv.x * xp[e] + wv.y * xp[e + 1] + wv.z * xp[e + 2] + wv.w * xp[e + 3];
      }
      red[t] = a;
    }
    __syncthreads();
    if (t < 64) {
      float qval = (red[t] + red[t + 64] + red[t + 128] + red[t + 192]
                    + bq[h * 64 + t]) * 0.125f;  // fold in 1/sqrt(64)
      qs[t] = qval;
      float bd = qval * bk[h * 64 + t];
      #pragma unroll
      for (int o = 32; o > 0; o >>= 1) bd += __shfl_xor(bd, o, 64);
      if (t == 0) bias_dot[b * NHEADS + h] = bd;
    }
    __syncthreads();
    // fold q̂ through Wk: wf[e] = sum_d qs[d] * Wk[(h*64+d)*512 + e]
    float a0 = 0.0f, a1 = 0.0f;
    const float* wkb = Wk + (size_t)(h * 64) * 512;
    for (int d = 0; d < 64; ++d) {
      float qd = qs[d];
      a0 += qd * wkb[d * 512 + t];
      a1 += qd * wkb[d * 512 + t + 256];
    }
    int bh = b * NHEADS + h;
    int e1 = t, e2 = t + 256;
    wfT4[(e1 >> 2) * 1024 + bh * 4 + (e1 & 3)] = a0;
    wfT4[(e2 >> 2) * 1024 + bh * 4 + (e2 & 3)] = a1;
  } else {
    // pe table rows j = bid-256, +256, ... (~4 rows per block)
    int e0 = t * 2;
    float dvp = __expf((float)e0 * PE_C);        // same expr as original trig
    for (int j = bid - 256; j < LSEQ; j += 256) {
      float arg = (float)j * dvp;
      float2 v;
      v.x = __sinf(arg);
      v.y = __cosf(arg);
      *(float2*)(pe_tab + (size_t)j * 512 + e0) = v;
    }
  }
  bar_signal(flags, 1);
  bar_finish(flags, go + 0, 1, NBLK);

  // ======================== Phase B ========================
  {
    float* rows = smem;                          // 8 rows x 516 (pad 4)
    for (int wi = bid; wi < 628; wi += NBLK) {
      __syncthreads();                           // protect smem reuse
      int r0  = (wi % 157) * 8;
      int bh0 = (wi / 157) * 64;
      #pragma unroll
      for (int i = 0; i < 4; ++i) {
        int fi = t + i * 256;                    // float4 index 0..1023
        int rr = fi >> 7;                        // local row
        int e  = (fi & 127) * 4;
        int rg = r0 + rr;
        float4 v;
        if (rg < 256) v = *(const float4*)(emb + (size_t)rg * 512 + e);
        else          v = *(const float4*)(pe_tab + (size_t)(rg - 256) * 512 + e);
        *(float4*)(&rows[rr * 516 + e]) = v;
      }
      __syncthreads();
      int w    = t >> 6, lane = t & 63;
      int bh   = bh0 + w * 16 + (lane & 15);     // wave-distinct bh strip
      int rp   = lane >> 4;                      // row pair within strip
      const float* rw0 = rows + (2 * rp) * 516;
      const float* rw1 = rows + (2 * rp + 1) * 516;
      const float* wp  = wfT4 + (size_t)bh * 4;
      float a0 = 0.0f, a1 = 0.0f;
      #pragma unroll 8
      for (int g = 0; g < 128; ++g) {
        float4 w4 = *(const float4*)(wp + (size_t)g * 1024);
        float4 v0 = *(const float4*)(rw0 + 4 * g);
        float4 v1 = *(const float4*)(rw1 + 4 * g);
        a0 += v0.x * w4.x + v0.y * w4.y + v0.z * w4.z + v0.w * w4.w;
        a1 += v1.x * w4.x + v1.y * w4.y + v1.z * w4.z + v1.w * w4.w;
      }
      float bd = (r0 < 256) ? bias_dot[bh] : 0.0f;
      int r = r0 + 2 * rp;
      MD[(size_t)r * 256 + bh]       = a0 + bd;
      MD[(size_t)(r + 1) * 256 + bh] = a1 + bd;
    }
  }
  bar_signal(flags, 2);
  bar_finish(flags, go + 16, 2, NBLK);

  // ======================== Phase C ========================
  {
    int jc = bid & 15, b = bid >> 4;             // exactly 1 item/block
    int n  = lengths[b];
    int j0 = jc * CHUNK;
    if (j0 < n) {                                // block-uniform guard
      int cnt = min(CHUNK, n - j0);
      float* sl   = smem;                        // [64][8] probs
      float* redw = smem + 512;                  // [4][8]
      float* m_sh = smem + 544;                  // [8]
      float* s_sh = smem + 552;                  // [8]
      int*   tk   = (int*)(smem + 560);          // [64]
      const float* Edot = MD;                    // [256 tok][256 bh] (+bias)
      const float* Pdot = MD + 256 * 256;        // [1000 pos][256 bh]

      if (t < CHUNK) tk[t] = data[b * LSEQ + j0 + ((t < cnt) ? t : 0)];
      __syncthreads();

      // scores: thread handles (jA,h) and (jB=jA+32,h)
      int h = t & 7, jA = t >> 3, jB = jA + 32;
      int bh8 = b * 8 + h;
      float sA = -INFINITY, sB = -INFINITY;
      if (jA < cnt)
        sA = Edot[(size_t)tk[jA] * 256 + bh8] + Pdot[(size_t)(j0 + jA) * 256 + bh8];
      if (jB < cnt)
        sB = Edot[(size_t)tk[jB] * 256 + bh8] + Pdot[(size_t)(j0 + jB) * 256 + bh8];

      int w = t >> 6;
      float mloc = fmaxf(sA, sB);
      #pragma unroll
      for (int o = 8; o < 64; o <<= 1) mloc = fmaxf(mloc, __shfl_xor(mloc, o, 64));
      if ((t & 63) < 8) redw[w * 8 + (t & 7)] = mloc;
      __syncthreads();
      if (t < 8)
        m_sh[t] = fmaxf(fmaxf(redw[t], redw[8 + t]),
                        fmaxf(redw[16 + t], redw[24 + t]));
      __syncthreads();
      float mh = m_sh[h];
      float pA = __expf(sA - mh);                // exp(-inf)=0 for invalid j
      float pB = __expf(sB - mh);
      sl[jA * 8 + h] = pA;
      sl[jB * 8 + h] = pB;
      float sloc = pA + pB;
      #pragma unroll
      for (int o = 8; o < 64; o <<= 1) sloc += __shfl_xor(sloc, o, 64);
      if ((t & 63) < 8) redw[w * 8 + (t & 7)] = sloc;
      __syncthreads();                           // also publishes sl[]
      if (t < 8) s_sh[t] = redw[t] + redw[8 + t] + redw[16 + t] + redw[24 + t];

      // y accumulation; wave owns e-slice, lane owns (sin,cos) pair
      int lane = t & 63;
      int e0i = w * 128 + lane * 2;
      float acc0[8] = {0, 0, 0, 0, 0, 0, 0, 0};
      float acc1[8] = {0, 0, 0, 0, 0, 0, 0, 0};
      const float* pe_row = pe_tab + (size_t)j0 * 512 + e0i;
      #pragma unroll 4
      for (int jj = 0; jj < cnt; ++jj) {
        int tok = tk[jj];
        float2 ev = *(const float2*)(emb + (size_t)tok * 512 + e0i);
        float2 pv = *(const float2*)(pe_row + (size_t)jj * 512);
        float x0 = ev.x + pv.x;
        float x1 = ev.y + pv.y;
        float4 pa = *(const float4*)(&sl[jj * 8]);
        float4 pb = *(const float4*)(&sl[jj * 8 + 4]);
        acc0[0] += pa.x * x0; acc1[0] += pa.x * x1;
        acc0[1] += pa.y * x0; acc1[1] += pa.y * x1;
        acc0[2] += pa.z * x0; acc1[2] += pa.z * x1;
        acc0[3] += pa.w * x0; acc1[3] += pa.w * x1;
        acc0[4] += pb.x * x0; acc1[4] += pb.x * x1;
        acc0[5] += pb.y * x0; acc1[5] += pb.y * x1;
        acc0[6] += pb.z * x0; acc1[6] += pb.z * x1;
        acc0[7] += pb.w * x0; acc1[7] += pb.w * x1;
      }
      size_t base = (size_t)(b * NCHUNK + jc) * 4096 + e0i;
      #pragma unroll
      for (int hh = 0; hh < 8; ++hh) {
        float2 o; o.x = acc0[hh]; o.y = acc1[hh];
        *(float2*)(y_part + base + hh * 512) = o;
      }
      if (t < 8) {
        float2 ms; ms.x = m_sh[t]; ms.y = s_sh[t];
        *(float2*)(mS + ((size_t)(b * NCHUNK + jc) * 8 + t) * 2) = ms;
      }
    }
  }
  bar_signal(flags, 3);
  if (bid >= 256) return;                        // no further work or reads
  bar_finish(flags, go + 32, 3, NBLK);

  // ======================== Phase D1: per-(b,h) combine + Wv matvec ========
  {
    int h = bid & 7, b = bid >> 3;
    float* ys  = smem;                           // 512
    float* red = smem + 512;                     // 256
    int n  = lengths[b];
    int nc = (n + CHUNK - 1) / CHUNK;
    float M = -INFINITY;
    for (int jc = 0; jc < nc; ++jc)
      M = fmaxf(M, mS[((size_t)(b * NCHUNK + jc) * 8 + h) * 2]);
    float S = 0.0f, s0 = 0.0f, s1 = 0.0f;
    for (int jc = 0; jc < nc; ++jc) {
      float2 ms = *(const float2*)(mS + ((size_t)(b * NCHUNK + jc) * 8 + h) * 2);
      float wgt = __expf(ms.x - M);
      S += wgt * ms.y;
      size_t base = (size_t)(b * NCHUNK + jc) * 4096 + h * 512;
      s0 += wgt * y_part[base + t];
      s1 += wgt * y_part[base + t + 256];
    }
    float inv = 1.0f / S;
    ys[t]       = s0 * inv;
    ys[t + 256] = s1 * inv;
    __syncthreads();
    // ctx slice = Wv_h · y_h + bv (4-way K-split, same red tree as split K4)
    int col = h * 64 + (t & 63);
    int kp  = t >> 6;
    const float* wr = Wv + (size_t)col * 512 + kp * 128;
    const float* xp = ys + kp * 128;
    float a = 0.0f;
    for (int e = 0; e < 128; e += 4) {
      float4 wv4 = *(const float4*)(wr + e);
      a += wv4.x * xp[e] + wv4.y * xp[e + 1] + wv4.z * xp[e + 2] + wv4.w * xp[e + 3];
    }
    red[t] = a;
    __syncthreads();
    if (t < 64)
      ctx_g[b * 512 + h * 64 + t] =
          red[t] + red[t + 64] + red[t + 128] + red[t + 192] + bv[h * 64 + t];
  }
  bar_signal(flags, 4);
  if (bid >= BATCH) return;                      // everyone else is done
  bar_finish(flags, go + 48, 4, 256);            // ctx written by blocks 0..255

  // ======================== Phase D2: MLP (blocks 0..31) ===================
  {
    int b = bid;
    float* xs   = smem;                          // 512
    float* red  = smem + 512;                    // 256
    float* hs_s = smem + 768;                    // 512
    float* o8   = smem + 1280;                   // 8
    xs[t]       = ctx_g[b * 512 + t];
    xs[t + 256] = ctx_g[b * 512 + t + 256];
    __syncthreads();
    // mlp1 (replicates split K5)
    for (int ch = 0; ch < 8; ++ch) {
      int col = ch * 64 + (t & 63);
      int kp  = t >> 6;
      const float* wr = W1 + (size_t)col * 512 + kp * 128;
      const float* xp = xs + kp * 128;
      float a = 0.0f;
      for (int e = 0; e < 128; e += 4) {
        float4 wv = *(const float4*)(wr + e);
        a += wv.x * xp[e] + wv.y * xp[e + 1] + wv.z * xp[e + 2] + wv.w * xp[e + 3];
      }
      red[t] = a;
      __syncthreads();
      if (t < 64) {
        float v = red[t] + red[t + 64] + red[t + 128] + red[t + 192] + b1[ch * 64 + t];
        hs_s[ch * 64 + t] = (v > 0.0f) ? v : 0.01f * v;
      }
      __syncthreads();
    }
    // mlp2 + mean + leaky (replicates split K6)
    int j = t >> 5, sub = t & 31;
    const float* w2r = W2 + (size_t)j * 512;
    float part = 0.0f;
    for (int e = sub * 16; e < sub * 16 + 16; e += 4) {
      float4 wv = *(const float4*)(w2r + e);
      float4 hv = *(const float4*)(hs_s + e);
      part += wv.x * hv.x + wv.y * hv.y + wv.z * hv.z + wv.w * hv.w;
    }
    #pragma unroll
    for (int o = 16; o > 0; o >>= 1) part += __shfl_xor(part, o, 64);
    if (sub == 0) o8[j] = fmaxf(part + b2[j], 0.0f);   // relu
    __syncthreads();
    if (t == 0) {
      float m = 0.0f;
      #pragma unroll
      for (int i = 0; i < 8; ++i) m += o8[i];
      m *= 0.125f;
      out[b] = (m > 0.0f) ? m : 0.01f * m;
    }
  }
}

// ---- launcher --------------------------------------------------------------
extern "C" void kernel_launch(void* const* d_in, const int* in_sizes, int n_in,
                              void* d_out, int out_size, void* d_ws, size_t ws_size,
                              hipStream_t stream) {
  const int*   data    = (const int*)d_in[0];
  const int*   lengths = (const int*)d_in[1];
  const float* emb     = (const float*)d_in[2];
  const float* Wq      = (const float*)d_in[3];
  const float* bq      = (const float*)d_in[4];
  const float* Wk      = (const float*)d_in[5];
  const float* bk      = (const float*)d_in[6];
  const float* Wv      = (const float*)d_in[7];
  const float* bv      = (const float*)d_in[8];
  const float* W1      = (const float*)d_in[9];
  const float* b1      = (const float*)d_in[10];
  const float* W2      = (const float*)d_in[11];
  const float* b2      = (const float*)d_in[12];
  float* out = (float*)d_out;

  char* ws = (char*)d_ws;
  float*    wfT4     = (float*)(ws);               //   524,288 B [e/4][256bh][4]
  float*    MD       = (float*)(ws + 524288);      // 1,286,144 B [1256][256bh]
  float*    bias_dot = (float*)(ws + 1810432);     //     1,024 B
  float*    mS       = (float*)(ws + 1811456);     //    32,768 B [b][16jc][h](m,S)
  float*    y_part   = (float*)(ws + 1844224);     // 8,388,608 B [b][16jc][8h][512]
  float*    pe_tab   = (float*)(ws + 10363904);    // 2,048,000 B [1000][512]
  float*    ctx_g    = (float*)(ws + 12411904);    //    65,536 B [32][512]
  unsigned* flags    = (unsigned*)(ws + 12477440); //     2,048 B arrival flags
  unsigned* go       = (unsigned*)(ws + 12479488); //       256 B go-words (64B apart)

  // zero flags + go (workspace poisoned each iteration); graph-capture-safe
  hipMemsetAsync(flags, 0, 2048 + 256, stream);

  fused_kernel<<<dim3(NBLK), dim3(256), 0, stream>>>(
      data, lengths, emb, Wq, bq, Wk, bk, Wv, bv, W1, b1, W2, b2,
      wfT4, bias_dot, MD, pe_tab, mS, y_part, ctx_g, flags, go, out);
}